// Round 10
// baseline (187.199 us; speedup 1.0000x reference)
//
#include <hip/hip_runtime.h>
#include <cstdint>
#include <cstddef>

typedef unsigned short u16;
typedef short short8 __attribute__((ext_vector_type(8)));
typedef float floatx4 __attribute__((ext_vector_type(4)));
typedef float floatx16 __attribute__((ext_vector_type(16)));

__device__ __forceinline__ float bf2f(u16 u) {
    union { unsigned int i; float f; } v; v.i = ((unsigned int)u) << 16; return v.f;
}
__device__ __forceinline__ u16 f2bf(float f) {
    union { float f; unsigned int i; } v; v.f = f;
    unsigned int u = v.i;
    return (u16)((u + 0x7fffu + ((u >> 16) & 1u)) >> 16);
}

#if __has_builtin(__builtin_amdgcn_exp2f)
#define EXP2F(x) __builtin_amdgcn_exp2f(x)
#else
#define EXP2F(x) exp2f(x)
#endif

// async global->LDS, 16B per lane; LDS dest = wave-uniform base + lane*16
__device__ __forceinline__ void gload_lds16(const u16* g, void* lds_wave_base) {
    __builtin_amdgcn_global_load_lds(
        (__attribute__((address_space(1))) void*)g,
        (__attribute__((address_space(3))) void*)lds_wave_base,
        16, 0, 0);
}

// counted-vmcnt barrier pair (T4)
#define WAITVM(N) asm volatile("s_waitcnt vmcnt(" #N ")" ::: "memory")
#define BARRIER_ACQ()                      \
    do {                                   \
        __builtin_amdgcn_s_barrier();      \
        asm volatile("" ::: "memory");     \
        __builtin_amdgcn_sched_barrier(0); \
    } while (0)
#define BARRIER_REL()                      \
    do {                                   \
        asm volatile("" ::: "memory");     \
        __builtin_amdgcn_s_barrier();      \
    } while (0)

// ---------------------------------------------------------------------------
// Convert+transpose 4 weight matrices (E x E, f32) -> bf16. Wt[n][k]=W[k][n].
// Matrix 0 (Wq) pre-scaled by log2(e)/32 -> attention uses exp2(S) directly.
// ---------------------------------------------------------------------------
__global__ void conv_transpose_k(const float* __restrict__ w0, const float* __restrict__ w1,
                                 const float* __restrict__ w2, const float* __restrict__ w3,
                                 u16* __restrict__ o0, u16* __restrict__ o1,
                                 u16* __restrict__ o2, u16* __restrict__ o3, int n) {
    __shared__ float t[32][33];
    const float* w; u16* o;
    switch (blockIdx.z) {
        case 0: w = w0; o = o0; break;
        case 1: w = w1; o = o1; break;
        case 2: w = w2; o = o2; break;
        default: w = w3; o = o3; break;
    }
    const float sc = (blockIdx.z == 0) ? 0.04508422f : 1.0f;  // log2(e)/32 on Wq
    int tx = threadIdx.x, ty = threadIdx.y;
    int x0 = blockIdx.x * 32, y0 = blockIdx.y * 32;
    t[ty][tx] = w[(size_t)(y0 + ty) * n + x0 + tx];
    __syncthreads();
    o[(size_t)(x0 + ty) * n + y0 + tx] = f2bf(t[tx][ty] * sc);
}

// ---------------------------------------------------------------------------
// Convert f32 -> bf16, vectorized.
// ---------------------------------------------------------------------------
__global__ void conv_k(const float* __restrict__ in, u16* __restrict__ out, int n) {
    int i = (blockIdx.x * blockDim.x + threadIdx.x) * 4;
    if (i >= n) return;
    float4 v = *(const float4*)&in[i];
    ushort4 o;
    o.x = f2bf(v.x); o.y = f2bf(v.y); o.z = f2bf(v.z); o.w = f2bf(v.w);
    *(ushort4*)&out[i] = o;
}

// ---------------------------------------------------------------------------
// Fused QKV GEMM v3 (unchanged, proven): counted-vmcnt pipeline, LDS-staged
// coalesced epilogue, V stored directly packed [bh][kblk][d][tloc].
// ---------------------------------------------------------------------------
#define QSTG(K0, BUF)                                                          \
    {                                                                          \
        _Pragma("unroll")                                                      \
        for (int it = 0; it < 2; ++it) {                                       \
            int idx = it * 256 + tid;                                          \
            int row = idx >> 2;                                                \
            int c8 = (idx & 3) * 8;                                            \
            size_t ldsoff = (size_t)(it * 256 + wave * 64) * 16;               \
            gload_lds16(&A[(size_t)(bm + row) * K + (K0) + c8],                \
                        (char*)smem + (BUF) * 8192 + ldsoff);                  \
            gload_lds16(&Bt[(size_t)(bn + row) * K + (K0) + c8],               \
                        (char*)smem + 16384 + (BUF) * 8192 + ldsoff);          \
        }                                                                      \
    }

__global__ __launch_bounds__(256, 3) void gemm_qkv(
    const u16* __restrict__ A, const u16* __restrict__ Bt,
    u16* __restrict__ qpk, u16* __restrict__ kpk, u16* __restrict__ vpk,
    int M, int T, int K) {
    __shared__ __align__(16) u16 smem[16384];

    const int tid = threadIdx.x;
    const int lane = tid & 63, wave = tid >> 6;
    const int wm = (wave >> 1) * 64, wn = (wave & 1) * 64;
    const int bm = blockIdx.x * 128, bn = blockIdx.y * 128;
    const int l15 = lane & 15, lq = lane >> 4;

    const int sec = bn >> 10;
    u16* dst = (sec == 0) ? qpk : (sec == 1) ? kpk : vpk;
    const int bnE = bn & 1023;

    floatx4 acc[4][4];
#pragma unroll
    for (int i = 0; i < 4; ++i)
#pragma unroll
        for (int j = 0; j < 4; ++j) acc[i][j] = (floatx4)0.0f;

    const int nkt = K / 32;
    QSTG(0, 0);

    for (int kt = 0; kt < nkt; ++kt) {
        const int cur = kt & 1;
        if (kt + 1 < nkt) {
            QSTG((kt + 1) * 32, cur ^ 1);
            WAITVM(4);
        } else {
            WAITVM(0);
        }
        BARRIER_ACQ();

        const u16* la = smem + cur * 4096;
        const u16* lb = smem + 8192 + cur * 4096;
        short8 af[4], bfr[4];
#pragma unroll
        for (int i = 0; i < 4; ++i) af[i] = *(const short8*)&la[(wm + i * 16 + l15) * 32 + lq * 8];
#pragma unroll
        for (int j = 0; j < 4; ++j) bfr[j] = *(const short8*)&lb[(wn + j * 16 + l15) * 32 + lq * 8];

#pragma unroll
        for (int i = 0; i < 4; ++i)
#pragma unroll
            for (int j = 0; j < 4; ++j)
                acc[i][j] = __builtin_amdgcn_mfma_f32_16x16x32_bf16(af[i], bfr[j], acc[i][j], 0, 0, 0);

        BARRIER_REL();
    }

    if (sec < 2) {
#pragma unroll
        for (int i = 0; i < 4; ++i)
#pragma unroll
            for (int r = 0; r < 4; ++r) {
                int trow = wm + i * 16 + lq * 4 + r;
                int s7 = ((trow >> 2) & 7) << 4;
#pragma unroll
                for (int j = 0; j < 4; ++j) {
                    int col = wn + j * 16 + l15;
                    smem[trow * 128 + (col ^ s7)] = f2bf(acc[i][j][r]);
                }
            }
        __syncthreads();
        const int rg = tid >> 3, cc = tid & 7;
#pragma unroll
        for (int p = 0; p < 4; ++p)
#pragma unroll
            for (int sfx = 0; sfx < 2; ++sfx) {
                int row = p * 32 + rg;
                int ch = cc + sfx * 8;
                short8 v = *(const short8*)&smem[row * 128 + ((ch * 8) ^ (((row >> 2) & 7) << 4))];
                int colE = bnE + ch * 8;
                int h = colE >> 6, d = colE & 63;
                int rowg = bm + row;
                int b = rowg >> 11, t = rowg & 2047;
                *(short8*)&dst[(((size_t)(b * 16 + h) * T) + t) * 64 + d] = v;
            }
    } else {
#pragma unroll
        for (int j = 0; j < 4; ++j) {
            int clo = wn + j * 16 + l15;
            int s7 = ((clo >> 2) & 7) << 4;
#pragma unroll
            for (int i = 0; i < 4; ++i)
#pragma unroll
                for (int r = 0; r < 4; ++r) {
                    int trow = wm + i * 16 + lq * 4 + r;
                    smem[clo * 128 + (trow ^ s7)] = f2bf(acc[i][j][r]);
                }
        }
        __syncthreads();
        const int rg = tid >> 3, cc = tid & 7;
        const int b = bm >> 11;
#pragma unroll
        for (int p = 0; p < 4; ++p)
#pragma unroll
            for (int sfx = 0; sfx < 2; ++sfx) {
                int clo = p * 32 + rg;
                int ch = cc + sfx * 8;
                short8 v = *(const short8*)&smem[clo * 128 + ((ch * 8) ^ (((clo >> 2) & 7) << 4))];
                int colE = bnE + clo;
                int h = colE >> 6, d = colE & 63;
                int t = (bm + ch * 8) & 2047;
                int kblk = t >> 6, tloc = t & 63;
                *(short8*)&dst[(((size_t)(b * 16 + h) * 32 + kblk) * 64 + d) * 64 + tloc] = v;
            }
    }
}

// ---------------------------------------------------------------------------
// FF GEMM v3 (unchanged, proven).
// ---------------------------------------------------------------------------
#define FSTG(K0, BUF)                                                          \
    {                                                                          \
        {                                                                      \
            int row = tid >> 2;                                                \
            int c8 = (tid & 3) * 8;                                            \
            size_t ldsoff = (size_t)(wave * 64) * 16;                          \
            gload_lds16(&A[(size_t)(bm + row) * K + (K0) + c8],                \
                        (char*)smemF + (BUF) * 4096 + ldsoff);                 \
        }                                                                      \
        _Pragma("unroll")                                                      \
        for (int it = 0; it < 2; ++it) {                                       \
            int idx = it * 256 + tid;                                          \
            int row = idx >> 2;                                                \
            int c8 = (idx & 3) * 8;                                            \
            size_t ldsoff = (size_t)(it * 256 + wave * 64) * 16;               \
            gload_lds16(&Bt[(size_t)(bn + row) * K + (K0) + c8],               \
                        (char*)smemF + 8192 + (BUF) * 8192 + ldsoff);          \
        }                                                                      \
    }

__global__ __launch_bounds__(256) void gemm64_bt(
    const u16* __restrict__ A, const u16* __restrict__ Bt, float* __restrict__ Cf,
    const float* __restrict__ bias, const u16* __restrict__ resid,
    int M, int N, int K) {
    __shared__ __align__(16) u16 smemF[12288];

    const int tid = threadIdx.x;
    const int lane = tid & 63, wave = tid >> 6;
    const int wm = (wave >> 1) * 32, wn = (wave & 1) * 64;
    const int bm = blockIdx.x * 64, bn = blockIdx.y * 128;
    const int l15 = lane & 15, lq = lane >> 4;

    floatx4 acc[2][4];
#pragma unroll
    for (int i = 0; i < 2; ++i)
#pragma unroll
        for (int j = 0; j < 4; ++j) acc[i][j] = (floatx4)0.0f;

    const int nkt = K / 32;
    FSTG(0, 0);

    for (int kt = 0; kt < nkt; ++kt) {
        const int cur = kt & 1;
        if (kt + 1 < nkt) {
            FSTG((kt + 1) * 32, cur ^ 1);
            WAITVM(3);
        } else {
            WAITVM(0);
        }
        BARRIER_ACQ();

        const u16* la = smemF + cur * 2048;
        const u16* lb = smemF + 4096 + cur * 2048 * 2;
        short8 af[2], bfr[4];
#pragma unroll
        for (int i = 0; i < 2; ++i) af[i] = *(const short8*)&la[(wm + i * 16 + l15) * 32 + lq * 8];
#pragma unroll
        for (int j = 0; j < 4; ++j) bfr[j] = *(const short8*)&lb[(wn + j * 16 + l15) * 32 + lq * 8];

#pragma unroll
        for (int i = 0; i < 2; ++i)
#pragma unroll
            for (int j = 0; j < 4; ++j)
                acc[i][j] = __builtin_amdgcn_mfma_f32_16x16x32_bf16(af[i], bfr[j], acc[i][j], 0, 0, 0);

        BARRIER_REL();
    }

#pragma unroll
    for (int i = 0; i < 2; ++i)
#pragma unroll
        for (int j = 0; j < 4; ++j)
#pragma unroll
            for (int r = 0; r < 4; ++r) {
                int row = bm + wm + i * 16 + lq * 4 + r;
                int col = bn + wn + j * 16 + l15;
                float v = acc[i][j][r];
                v = fmaxf(v + bias[col], 0.0f) + bf2f(resid[(size_t)row * N + col]);
                Cf[(size_t)row * N + col] = v;
            }
}

// ---------------------------------------------------------------------------
// Flash attention v19: 32x32x16 MFMA. Per wave: 32 q-rows served by 16
// ds_read_b128 per 64-chunk (2x the q-rows per LDS read vs 16x16 — the
// saturated per-CU LDS pipe identified in rounds 5-9). Block = 2 waves =
// 64 q-rows; grid stays (32,32) = 1024 blocks; LDS 32 KB (5 blocks/CU cap).
//
// Layouts (C/D verified m74/m101; A/B = same extension as verified 16x16x32):
//   A/B-frag: row|col = l&31, k = (l>>5)*8 + j
//   C/D:      col = l&31, row = (reg&3) + 8*(reg>>2) + 4*(l>>5)
// K-row permutation sigma = swap bits 2<->3 of the A-row index (involution):
// LDS K-row r holds global k-row sigma(r) => lane's S^T regs 8s..8s+7 of tile
// t pack straight into the PV A-operand for k = kc0+32t+16s+8hi+j (16 cvt_pk,
// no LDS round-trip, no cross-lane). Masking uses
//   k = kc0 + 32t + j + 4*(g&1) + 16*(g>>1) + 8*hi   (reg = 4g+j).
// Slot swizzle: phys_slot = (log_slot + (row&7)) & 7 for both K and V,
// staged via pre-swizzled global source (rule #21). lsum: one shfl_xor(32).
// ---------------------------------------------------------------------------
#define STAGE32(KT, BUF)                                                         \
    {                                                                            \
        _Pragma("unroll")                                                        \
        for (int m = 0; m < 4; ++m) {                                            \
            int i_ = m * 128 + tid;                                              \
            int r_ = i_ >> 3, s_ = i_ & 7;                                       \
            int sr_ = (r_ & 0x33) | ((r_ & 4) << 1) | ((r_ & 8) >> 1);           \
            int sl_ = ((s_ - (r_ & 7)) & 7) * 8;                                 \
            size_t lb_ = (size_t)(m * 2048 + wave * 1024);                       \
            gload_lds16(kb + (size_t)((KT) * 64 + sr_) * 64 + sl_,               \
                        (char*)kbuf + (BUF) * 8192 + lb_);                       \
            gload_lds16(vp + (size_t)(KT) * 4096 + (size_t)r_ * 64 + sl_,        \
                        (char*)vbuf + (BUF) * 8192 + lb_);                       \
        }                                                                        \
    }

__global__ __launch_bounds__(128) void attn19_k(
    const u16* __restrict__ qpk, const u16* __restrict__ kpk,
    const u16* __restrict__ vpack, const float* __restrict__ xf,
    u16* __restrict__ y, int T, int E) {
    __shared__ u16 kbuf[2][64 * 64];        // K, rows sigma-permuted, slots rotated
    __shared__ u16 vbuf[2][64 * 64];        // V packed [d][tloc], slots rotated

    const int tid = threadIdx.x;            // 0..127
    const int lane = tid & 63, wave = tid >> 6;
    const int l31 = lane & 31, hi = lane >> 5;
    const int bh = blockIdx.x;              // head->XCD affinity
    const int b = bh >> 4, h = bh & 15;
    const int qb = 31 - (int)blockIdx.y;    // LPT: longest blocks dispatch first

    const u16* qp = qpk + (size_t)bh * T * 64;
    const u16* kb = kpk + (size_t)bh * T * 64;
    const u16* vp = vpack + (size_t)bh * T * 64;    // [T/64][64][64] blocks

    const int f = l31 & 7;                  // slot-rotation key (rows l31+32t share it)
    const int qt = qb * 64 + wave * 32;     // this wave's 32 q-rows
    const int qg = qt + l31;                // lane's q-row
    const int nkb = qb + 1;

    // Q as B-operand: aq[c] covers dims 16c + 8hi .. +8 of row qg
    short8 aq[4];
#pragma unroll
    for (int c = 0; c < 4; ++c)
        aq[c] = *(const short8*)&qp[(size_t)qg * 64 + c * 16 + hi * 8];

    floatx16 o[2];
    o[0] = (floatx16)0.0f; o[1] = (floatx16)0.0f;
    float lsum = 0.0f;

    STAGE32(0, 0);

#pragma unroll 1
    for (int kt = 0; kt < nkb; ++kt) {
        const int kc0 = kt * 64;
        const int cur = kt & 1;
        const int curoff = cur * 8192;

        if (kt + 1 < nkb) {
            STAGE32(kt + 1, cur ^ 1);
            WAITVM(8);
        } else {
            WAITVM(0);
        }
        BARRIER_ACQ();

        // ---- S^T = K Q^T : 2 k-tiles x 4 K-steps of 32x32x16 ----
        floatx16 st[2];
        __builtin_amdgcn_s_setprio(1);
#pragma unroll
        for (int t = 0; t < 2; ++t) {
            floatx16 sa = (floatx16)0.0f;
#pragma unroll
            for (int c = 0; c < 4; ++c) {
                int off = (l31 + 32 * t) * 128 + (((2 * c + hi + f) & 7) * 16);
                short8 bk = *(const short8*)((const char*)kbuf + curoff + off);
                sa = __builtin_amdgcn_mfma_f32_32x32x16_bf16(bk, aq[c], sa, 0, 0, 0);
            }
            st[t] = sa;
        }
        __builtin_amdgcn_s_setprio(0);

        // ---- softmax numerator (exp2 direct), pack into PV A-operands ----
        const bool partial = (kt == qb);
        unsigned int pk[2][8];
#pragma unroll
        for (int t = 0; t < 2; ++t)
#pragma unroll
            for (int g = 0; g < 4; ++g) {
                float e0, e1, e2, e3;
                const int kgb = kc0 + 32 * t + 4 * (g & 1) + 16 * (g >> 1) + 8 * hi;
                if (partial) {
                    e0 = (kgb + 0 <= qg) ? EXP2F(st[t][g * 4 + 0]) : 0.0f;
                    e1 = (kgb + 1 <= qg) ? EXP2F(st[t][g * 4 + 1]) : 0.0f;
                    e2 = (kgb + 2 <= qg) ? EXP2F(st[t][g * 4 + 2]) : 0.0f;
                    e3 = (kgb + 3 <= qg) ? EXP2F(st[t][g * 4 + 3]) : 0.0f;
                } else {
                    e0 = EXP2F(st[t][g * 4 + 0]);
                    e1 = EXP2F(st[t][g * 4 + 1]);
                    e2 = EXP2F(st[t][g * 4 + 2]);
                    e3 = EXP2F(st[t][g * 4 + 3]);
                }
                lsum += (e0 + e1) + (e2 + e3);
                unsigned int w0, w1;
                asm("v_cvt_pk_bf16_f32 %0, %1, %2" : "=v"(w0) : "v"(e0), "v"(e1));
                asm("v_cvt_pk_bf16_f32 %0, %1, %2" : "=v"(w1) : "v"(e2), "v"(e3));
                pk[t][g * 2 + 0] = w0;
                pk[t][g * 2 + 1] = w1;
            }

        // ---- O += P V : P regs feed A directly (sigma alignment) ----
        __builtin_amdgcn_s_setprio(1);
#pragma unroll
        for (int t = 0; t < 2; ++t)
#pragma unroll
            for (int s = 0; s < 2; ++s) {
                union { unsigned int u[4]; short8 v; } ap;
                ap.u[0] = pk[t][4 * s + 0];
                ap.u[1] = pk[t][4 * s + 1];
                ap.u[2] = pk[t][4 * s + 2];
                ap.u[3] = pk[t][4 * s + 3];
#pragma unroll
                for (int dt = 0; dt < 2; ++dt) {
                    int off = (l31 + 32 * dt) * 128 + (((4 * t + 2 * s + hi + f) & 7) * 16);
                    short8 bv = *(const short8*)((const char*)vbuf + curoff + off);
                    o[dt] = __builtin_amdgcn_mfma_f32_32x32x16_bf16(ap.v, bv, o[dt], 0, 0, 0);
                }
            }
        __builtin_amdgcn_s_setprio(0);

        BARRIER_REL();
    }

    // ---- lsum: partner half-lane holds the other 32 k per q ----
    lsum += __shfl_xor(lsum, 32, 64);

    // ---- epilogue: y = x + O/l ; O row = (reg&3)+8*(reg>>2)+4*hi ----
    float rl[16];
#pragma unroll
    for (int g = 0; g < 4; ++g)
#pragma unroll
        for (int j = 0; j < 4; ++j)
            rl[g * 4 + j] = 1.0f / __shfl(lsum, j + 8 * g + 4 * hi, 64);

    const float* xp = xf + (size_t)b * T * E + (size_t)h * 64;
    u16* yp = y + (size_t)b * T * E + (size_t)h * 64;
#pragma unroll
    for (int dt = 0; dt < 2; ++dt)
#pragma unroll
        for (int g = 0; g < 4; ++g)
#pragma unroll
            for (int j = 0; j < 4; ++j) {
                int rowg = qt + j + 8 * g + 4 * hi;
                int col = dt * 32 + l31;
                float val = o[dt][g * 4 + j] * rl[g * 4 + j];
                float res = __builtin_nontemporal_load(xp + (size_t)rowg * E + col);
                yp[(size_t)rowg * E + col] = f2bf(res + val);
            }
}

// ---------------------------------------------------------------------------
extern "C" void kernel_launch(void* const* d_in, const int* in_sizes, int n_in,
                              void* d_out, int out_size, void* d_ws, size_t ws_size,
                              hipStream_t stream) {
    const int B = 2, T = 2048, E = 1024;
    const int M = B * T;  // 4096

    const float* x  = (const float*)d_in[0];
    const float* Wq = (const float*)d_in[1];
    const float* Wk = (const float*)d_in[2];
    const float* Wv = (const float*)d_in[3];
    const float* Wf = (const float*)d_in[4];
    const float* bf = (const float*)d_in[5];
    float* out = (float*)d_out;

    u16* ws = (u16*)d_ws;
    const size_t WN = (size_t)E * E;
    const size_t XN = (size_t)M * E;
    u16* Wqkv  = ws;
    u16* WfT   = ws + 3 * WN;
    u16* xb    = ws + 4 * WN;
    u16* qpk   = ws + 4 * WN + XN;
    u16* kpk   = ws + 4 * WN + 2 * XN;
    u16* vpk   = ws + 4 * WN + 3 * XN;
    u16* yb    = ws + 4 * WN + 4 * XN;
    // total: 4*WN + 5*XN = 48 MB

    conv_transpose_k<<<dim3(E / 32, E / 32, 4), dim3(32, 32), 0, stream>>>(
        Wq, Wk, Wv, Wf, Wqkv, Wqkv + WN, Wqkv + 2 * WN, WfT, E);
    conv_k<<<(int)(XN / 1024), 256, 0, stream>>>(x, xb, (int)XN);

    gemm_qkv<<<dim3(M / 128, 3 * E / 128), 256, 0, stream>>>(
        xb, Wqkv, qpk, kpk, vpk, M, T, E);

    // grid (bh=32, qb=32), 128 threads (2 waves), LPT order
    attn19_k<<<dim3(B * 16, T / 64), 128, 0, stream>>>(qpk, kpk, vpk, x, yb, T, E);

    gemm64_bt<<<dim3(M / 64, E / 128), 256, 0, stream>>>(yb, WfT, out, bf, yb, M, E, E);
}